// Round 2
// baseline (210.830 us; speedup 1.0000x reference)
//
#include <hip/hip_runtime.h>
#include <hip/hip_bf16.h>

#define N_TOT 25200
#define L0_END 19200
#define L1_END 24000
#define NCLS 80
#define CAP 1024

__device__ __constant__ float c_AW[9] = {12.f,19.f,40.f,36.f,76.f,72.f,142.f,192.f,459.f};
__device__ __constant__ float c_AH[9] = {16.f,36.f,28.f,75.f,55.f,146.f,110.f,243.f,401.f};

// ---------------- decode: one thread per anchor ----------------
__global__ __launch_bounds__(256)
void decode_kernel(const float* __restrict__ p0,
                   const float* __restrict__ p1,
                   const float* __restrict__ p2,
                   float4* __restrict__ wboxes,
                   float* __restrict__ wconf,
                   int*   __restrict__ wcls,
                   float* __restrict__ out)
{
    int n = blockIdx.x * 256 + threadIdx.x;
    if (n >= N_TOT) return;

    const float* p; int f, strd, base, lvl;
    if (n < L0_END)      { p = p0; f = 80; strd = 8;  base = 0;      lvl = 0; }
    else if (n < L1_END) { p = p1; f = 40; strd = 16; base = L0_END; lvl = 1; }
    else                 { p = p2; f = 20; strd = 32; base = L1_END; lvl = 2; }

    int r  = n - base;
    int hw = r / 3;
    int a  = r - hw * 3;
    int HW = f * f;
    int gx = hw % f;
    int gy = hw / f;
    const float* cell = p + hw;     // p[ch*HW + hw] == pred[ch, y, x]

    float obj = cell[a * HW];

    // class logits: channels 3 + a*80 + c
    const float* clsp = cell + (3 + a * NCLS) * HW;
    float m = clsp[0];
    #pragma unroll 8
    for (int c = 1; c < NCLS; ++c) m = fmaxf(m, clsp[c * HW]);
    float s = 0.f;
    float bestp = -1.f;
    int amax = 0;
    #pragma unroll 8
    for (int c = 0; c < NCLS; ++c) {
        float pc = expf(clsp[c * HW] - m);
        s += pc;
        if (pc > bestp) { bestp = pc; amax = c; }  // strict > : first max wins, matches np.argmax
    }
    float sig  = 1.f / (1.f + expf(-obj));
    float conf = sig * (bestp / s);   // == max(scores) (monotone map, same op order as ref)

    // reg: channels 243 + a*4 + j
    const float* regp = cell + (243 + a * 4) * HW;
    float tx = regp[0];
    float ty = regp[HW];
    float tw = regp[2 * HW];
    float th = regp[3 * HW];
    float sx = 1.f / (1.f + expf(-tx));
    float sy = 1.f / (1.f + expf(-ty));
    float cx = (sx + (float)gx) * (float)strd;
    float cy = (sy + (float)gy) * (float)strd;
    int ai = lvl * 3 + a;
    float w  = expf(tw) * c_AW[ai];
    float h  = expf(th) * c_AH[ai];
    float hx = w * 0.5f, hy = h * 0.5f;     // *0.5 exact, matches ref
    float x1 = (cx - hx) / 640.0f;          // divide AFTER, like ref: (xy-wh/2)/IMG
    float y1 = (cy - hy) / 640.0f;
    float x2 = (cx + hx) / 640.0f;
    float y2 = (cy + hy) / 640.0f;
    x1 = fminf(fmaxf(x1, 0.f), 1.f);
    y1 = fminf(fmaxf(y1, 0.f), 1.f);
    x2 = fminf(fmaxf(x2, 0.f), 1.f);
    y2 = fminf(fmaxf(y2, 0.f), 1.f);

    wboxes[n] = make_float4(x1, y1, x2, y2);
    wconf[n]  = conf;
    wcls[n]   = amax;

    // outputs (float32), flat layout: bboxes [25200*4] | conf [25200] | cls [25200] | keep [25200]
    out[n * 4 + 0] = x1;
    out[n * 4 + 1] = y1;
    out[n * 4 + 2] = x2;
    out[n * 4 + 3] = y2;
    out[100800 + n] = conf;
    out[126000 + n] = (float)amax;
    out[151200 + n] = 0.0f;   // keep default: false
}

// ---------------- per-class NMS: one block per class ----------------
__global__ __launch_bounds__(256)
void nms_kernel(const float4* __restrict__ wboxes,
                const float*  __restrict__ wconf,
                const int*    __restrict__ wcls,
                float* __restrict__ out_keep)
{
    const int c = blockIdx.x;
    __shared__ int cnt;
    __shared__ unsigned int skey[CAP];   // conf bits (conf > 0 always -> bit order == float order)
    __shared__ int sidx[CAP];            // original anchor index
    __shared__ int order[CAP];           // order[rank] = element
    __shared__ float sx1[CAP], sy1[CAP], sx2[CAP], sy2[CAP], sarea[CAP];
    __shared__ int gidx[CAP];
    __shared__ unsigned char supp[CAP];

    if (threadIdx.x == 0) cnt = 0;
    __syncthreads();

    // gather valid boxes of this class
    for (int i = threadIdx.x; i < N_TOT; i += 256) {
        if (wcls[i] == c) {
            float cf = wconf[i];
            if (cf >= 0.001f) {          // == (cf_f32 >= 0.001 as f64)
                int pos = atomicAdd(&cnt, 1);
                if (pos < CAP) { skey[pos] = __float_as_uint(cf); sidx[pos] = i; }
            }
        }
    }
    __syncthreads();
    int M = min(cnt, CAP);

    // rank sort: conf desc, tie -> smaller original index (stable argsort(-scores))
    for (int e = threadIdx.x; e < M; e += 256) {
        unsigned ke = skey[e];
        int ie = sidx[e];
        int rank = 0;
        for (int j = 0; j < M; ++j) {
            unsigned kj = skey[j];
            rank += (kj > ke) || (kj == ke && sidx[j] < ie);
        }
        order[rank] = e;
    }
    __syncthreads();

    // gather sorted, offset boxes (offset rounding matters: ref computes IoU on offset boxes!)
    float off = 4.0f * (float)c;
    for (int rr = threadIdx.x; rr < M; rr += 256) {
        int e  = order[rr];
        int gi = sidx[e];
        float4 b = wboxes[gi];
        float x1 = b.x + off, y1 = b.y + off, x2 = b.z + off, y2 = b.w + off;
        sx1[rr] = x1; sy1[rr] = y1; sx2[rr] = x2; sy2[rr] = y2;
        sarea[rr] = (x2 - x1) * (y2 - y1);
        gidx[rr] = gi;
        supp[rr] = 0;
    }
    __syncthreads();

    // faithful sequential greedy
    for (int i = 0; i < M; ++i) {
        if (!supp[i]) {                      // uniform branch (broadcast LDS read)
            if (threadIdx.x == 0) out_keep[gidx[i]] = 1.0f;
            float bx1 = sx1[i], by1 = sy1[i], bx2 = sx2[i], by2 = sy2[i], ba = sarea[i];
            for (int j = i + 1 + (int)threadIdx.x; j < M; j += 256) {
                if (!supp[j]) {
                    float xx1 = fmaxf(bx1, sx1[j]);
                    float yy1 = fmaxf(by1, sy1[j]);
                    float xx2 = fminf(bx2, sx2[j]);
                    float yy2 = fminf(by2, sy2[j]);
                    float w = fmaxf(1e-28f, xx2 - xx1);
                    float h = fmaxf(1e-28f, yy2 - yy1);
                    float inter = w * h;
                    float ovr = inter / (ba + sarea[j] - inter + 1e-14f);
                    if (ovr >= 0.6f) supp[j] = 1;   // == (ovr_f32 > 0.6 as f64)
                }
            }
        }
        __syncthreads();
    }
}

extern "C" void kernel_launch(void* const* d_in, const int* in_sizes, int n_in,
                              void* d_out, int out_size, void* d_ws, size_t ws_size,
                              hipStream_t stream) {
    const float* p0 = (const float*)d_in[0];
    const float* p1 = (const float*)d_in[1];
    const float* p2 = (const float*)d_in[2];
    float* out = (float*)d_out;

    char* ws = (char*)d_ws;
    float4* wboxes = (float4*)ws;                // 25200*16 = 403200 B
    float*  wconf  = (float*)(ws + 403200);      // 25200*4
    int*    wcls   = (int*)(ws + 504000);        // 25200*4  (total 604800 B)

    decode_kernel<<<(N_TOT + 255) / 256, 256, 0, stream>>>(p0, p1, p2, wboxes, wconf, wcls, out);
    nms_kernel<<<NCLS, 256, 0, stream>>>(wboxes, wconf, wcls, out + 151200);
}

// Round 3
// 175.054 us; speedup vs baseline: 1.2044x; 1.2044x over previous
//
#include <hip/hip_runtime.h>

#define N_TOT 25200
#define L0_END 19200
#define L1_END 24000
#define NCLS 80
#define CAP 512          // max boxes per class (expected ~315, 5-sigma ~403)
#define NW 8             // 512 bits -> 8 u64 words per mask row

__device__ __constant__ float c_AW[9] = {12.f,19.f,40.f,36.f,76.f,72.f,142.f,192.f,459.f};
__device__ __constant__ float c_AH[9] = {16.f,36.f,28.f,75.f,55.f,146.f,110.f,243.f,401.f};

// ---------------- decode: 4 lanes per anchor ----------------
__global__ __launch_bounds__(256)
void decode_kernel(const float* __restrict__ p0,
                   const float* __restrict__ p1,
                   const float* __restrict__ p2,
                   float4* __restrict__ wboxes,
                   float* __restrict__ wconf,
                   int*   __restrict__ wcls,
                   float* __restrict__ out)
{
    int t = blockIdx.x * 256 + threadIdx.x;
    int n = t >> 2;          // anchor
    int q = t & 3;           // lane-in-group: handles classes c = 4k+q
    if (n >= N_TOT) return;

    const float* p; int f, strd, base, lvl;
    if (n < L0_END)      { p = p0; f = 80; strd = 8;  base = 0;      lvl = 0; }
    else if (n < L1_END) { p = p1; f = 40; strd = 16; base = L0_END; lvl = 1; }
    else                 { p = p2; f = 20; strd = 32; base = L1_END; lvl = 2; }

    int r  = n - base;
    int hw = r / 3;
    int a  = r - hw * 3;
    int HW = f * f;
    int gx = hw % f;
    int gy = hw / f;
    const float* cell = p + hw;                    // p[ch*HW + hw]
    const float* clsp = cell + (3 + a * NCLS) * HW;

    // load my 20 logits (classes 4k+q) into registers
    float v[20];
    #pragma unroll
    for (int k = 0; k < 20; ++k) v[k] = clsp[(4 * k + q) * HW];

    float lmax = v[0];
    #pragma unroll
    for (int k = 1; k < 20; ++k) lmax = fmaxf(lmax, v[k]);
    float gm = lmax;
    gm = fmaxf(gm, __shfl_xor(gm, 1));
    gm = fmaxf(gm, __shfl_xor(gm, 2));             // group max (exact)

    float ls = 0.f, bp = -1.f; int ba_ = 0;
    #pragma unroll
    for (int k = 0; k < 20; ++k) {
        float pc = expf(v[k] - gm);
        ls += pc;
        if (pc > bp) { bp = pc; ba_ = 4 * k + q; } // first-wins within increasing c
    }
    float gs = ls;
    gs += __shfl_xor(gs, 1);
    gs += __shfl_xor(gs, 2);                       // group sum (tree; ~1e-7 reorder)
    // argmax combine: larger p wins; tie -> smaller class index (np.argmax first-wins)
    {
        float bp2 = __shfl_xor(bp, 1); int ba2 = __shfl_xor(ba_, 1);
        if (bp2 > bp || (bp2 == bp && ba2 < ba_)) { bp = bp2; ba_ = ba2; }
        bp2 = __shfl_xor(bp, 2); ba2 = __shfl_xor(ba_, 2);
        if (bp2 > bp || (bp2 == bp && ba2 < ba_)) { bp = bp2; ba_ = ba2; }
    }

    if (q != 0) return;                            // leader finishes the anchor

    float obj = cell[a * HW];
    float sig  = 1.f / (1.f + expf(-obj));
    float conf = sig * (bp / gs);

    const float* regp = cell + (243 + a * 4) * HW;
    float tx = regp[0];
    float ty = regp[HW];
    float tw = regp[2 * HW];
    float th = regp[3 * HW];
    float sx = 1.f / (1.f + expf(-tx));
    float sy = 1.f / (1.f + expf(-ty));
    float cx = (sx + (float)gx) * (float)strd;
    float cy = (sy + (float)gy) * (float)strd;
    int ai = lvl * 3 + a;
    float w  = expf(tw) * c_AW[ai];
    float h  = expf(th) * c_AH[ai];
    float hx = w * 0.5f, hy = h * 0.5f;
    float x1 = (cx - hx) / 640.0f;
    float y1 = (cy - hy) / 640.0f;
    float x2 = (cx + hx) / 640.0f;
    float y2 = (cy + hy) / 640.0f;
    x1 = fminf(fmaxf(x1, 0.f), 1.f);
    y1 = fminf(fmaxf(y1, 0.f), 1.f);
    x2 = fminf(fmaxf(x2, 0.f), 1.f);
    y2 = fminf(fmaxf(y2, 0.f), 1.f);

    wboxes[n] = make_float4(x1, y1, x2, y2);
    wconf[n]  = conf;
    wcls[n]   = ba_;

    out[n * 4 + 0] = x1;
    out[n * 4 + 1] = y1;
    out[n * 4 + 2] = x2;
    out[n * 4 + 3] = y2;
    out[100800 + n] = conf;
    out[126000 + n] = (float)ba_;
    out[151200 + n] = 0.0f;                        // keep default
}

// ---------------- per-class NMS: mask build + wave-synchronous scan ----------------
__global__ __launch_bounds__(256)
void nms_kernel(const float4* __restrict__ wboxes,
                const float*  __restrict__ wconf,
                const int*    __restrict__ wcls,
                float* __restrict__ out_keep)
{
    const int c = blockIdx.x;
    __shared__ int cnt;
    __shared__ unsigned int skey[CAP];
    __shared__ int sidx[CAP];
    __shared__ float sx1[CAP], sy1[CAP], sx2[CAP], sy2[CAP], sarea[CAP];
    __shared__ int gidx[CAP];
    __shared__ unsigned long long smask[CAP * NW]; // 32 KB: bit (i,j)=1 iff IoU(i,j)>=0.6, j>i

    const int tid = threadIdx.x;
    if (tid == 0) cnt = 0;
    __syncthreads();

    // gather valid boxes of this class
    for (int i = tid; i < N_TOT; i += 256) {
        if (wcls[i] == c) {
            float cf = wconf[i];
            if (cf >= 0.001f) {                    // == (cf_f32 >= 0.001 as f64)
                int pos = atomicAdd(&cnt, 1);
                if (pos < CAP) { skey[pos] = __float_as_uint(cf); sidx[pos] = i; }
            }
        }
    }
    __syncthreads();
    const int M = min(cnt, CAP);

    // rank sort (conf desc, tie -> smaller original index) + scatter sorted offset boxes
    const float off = 4.0f * (float)c;
    for (int e = tid; e < M; e += 256) {
        unsigned ke = skey[e];
        int ie = sidx[e];
        int rank = 0;
        for (int j = 0; j < M; ++j) {              // broadcast LDS reads
            unsigned kj = skey[j];
            rank += (kj > ke) || (kj == ke && sidx[j] < ie);
        }
        float4 b = wboxes[ie];
        float x1 = b.x + off, y1 = b.y + off, x2 = b.z + off, y2 = b.w + off;
        sx1[rank] = x1; sy1[rank] = y1; sx2[rank] = x2; sy2[rank] = y2;
        sarea[rank] = (x2 - x1) * (y2 - y1);
        gidx[rank] = ie;
    }
    __syncthreads();

    // build suppression matrix: row r = which later boxes r would suppress
    for (int rr = tid; rr < M; rr += 256) {        // consecutive rows/lane -> stride-1 LDS
        float bx1 = sx1[rr], by1 = sy1[rr], bx2 = sx2[rr], by2 = sy2[rr], ba = sarea[rr];
        int w0 = (rr + 1) >> 6;
        for (int w = 0; w < w0; ++w) smask[rr * NW + w] = 0ull;
        for (int w = w0; w < NW; ++w) {
            unsigned long long bits = 0ull;
            int jlo = max(rr + 1, w * 64);
            int jhi = min(M, w * 64 + 64);
            for (int j = jlo; j < jhi; ++j) {
                float xx1 = fmaxf(bx1, sx1[j]);
                float yy1 = fmaxf(by1, sy1[j]);
                float xx2 = fminf(bx2, sx2[j]);
                float yy2 = fminf(by2, sy2[j]);
                float ww = fmaxf(1e-28f, xx2 - xx1);
                float hh = fmaxf(1e-28f, yy2 - yy1);
                float inter = ww * hh;
                float ovr = inter / (ba + sarea[j] - inter + 1e-14f); // same op order as ref
                bits |= (unsigned long long)(ovr >= 0.6f) << (j & 63);
            }
            smask[rr * NW + w] = bits;
        }
    }
    __syncthreads();

    // wave-synchronous greedy scan: lane l holds 'removed' word l (l<8); others shadow
    if (tid < 64) {
        const int lw = tid & 7;
        unsigned long long rem = 0ull;
        for (int i = 0; i < M; ++i) {
            unsigned long long row = smask[i * NW + lw];          // load overlaps shfl
            unsigned long long rw = __shfl(rem, i >> 6);
            if (!((rw >> (i & 63)) & 1ull)) rem |= row;           // kept -> suppress its row
        }
        // keep = !removed
        #pragma unroll
        for (int w = 0; w < NW; ++w) {
            unsigned long long rv = __shfl(rem, w);
            int i = w * 64 + tid;
            if (i < M && !((rv >> tid) & 1ull)) out_keep[gidx[i]] = 1.0f;
        }
    }
}

extern "C" void kernel_launch(void* const* d_in, const int* in_sizes, int n_in,
                              void* d_out, int out_size, void* d_ws, size_t ws_size,
                              hipStream_t stream) {
    const float* p0 = (const float*)d_in[0];
    const float* p1 = (const float*)d_in[1];
    const float* p2 = (const float*)d_in[2];
    float* out = (float*)d_out;

    char* ws = (char*)d_ws;
    float4* wboxes = (float4*)ws;                // 25200*16 = 403200 B
    float*  wconf  = (float*)(ws + 403200);      // 25200*4
    int*    wcls   = (int*)(ws + 504000);        // 25200*4  (total 604800 B)

    decode_kernel<<<(N_TOT * 4 + 255) / 256, 256, 0, stream>>>(p0, p1, p2, wboxes, wconf, wcls, out);
    nms_kernel<<<NCLS, 256, 0, stream>>>(wboxes, wconf, wcls, out + 151200);
}

// Round 4
// 88.214 us; speedup vs baseline: 2.3900x; 1.9844x over previous
//
#include <hip/hip_runtime.h>

typedef unsigned long long u64;
typedef unsigned int u32;

#define N_TOT 25200
#define L0_END 19200
#define L1_END 24000
#define NCLS 80
#define CAP 512           // max boxes/class; E[M]=315, sigma~17.6 -> +11 sigma
#define NW 8              // 512 bits -> 8 u64 words
#define CNT_STRIDE 16     // ints; 64B between class counters (atomic contention)

__device__ __constant__ float c_AW[9] = {12.f,19.f,40.f,36.f,76.f,72.f,142.f,192.f,459.f};
__device__ __constant__ float c_AH[9] = {16.f,36.f,28.f,75.f,55.f,146.f,110.f,243.f,401.f};

// ---------------- decode + bucket: 4 lanes per anchor ----------------
__global__ __launch_bounds__(256)
void decode_kernel(const float* __restrict__ p0,
                   const float* __restrict__ p1,
                   const float* __restrict__ p2,
                   int* __restrict__ cnt,
                   u64* __restrict__ bucket,
                   float* __restrict__ out)
{
    int t = blockIdx.x * 256 + threadIdx.x;
    int n = t >> 2;          // anchor
    int q = t & 3;           // lane-in-group: classes c = 4k+q
    if (n >= N_TOT) return;

    const float* p; int f, strd, base, lvl;
    if (n < L0_END)      { p = p0; f = 80; strd = 8;  base = 0;      lvl = 0; }
    else if (n < L1_END) { p = p1; f = 40; strd = 16; base = L0_END; lvl = 1; }
    else                 { p = p2; f = 20; strd = 32; base = L1_END; lvl = 2; }

    int r  = n - base;
    int hw = r / 3;
    int a  = r - hw * 3;
    int HW = f * f;
    int gx = hw % f;
    int gy = hw / f;
    const float* cell = p + hw;
    const float* clsp = cell + (3 + a * NCLS) * HW;

    float v[20];
    #pragma unroll
    for (int k = 0; k < 20; ++k) v[k] = clsp[(4 * k + q) * HW];

    float lmax = v[0];
    #pragma unroll
    for (int k = 1; k < 20; ++k) lmax = fmaxf(lmax, v[k]);
    float gm = lmax;
    gm = fmaxf(gm, __shfl_xor(gm, 1));
    gm = fmaxf(gm, __shfl_xor(gm, 2));

    float ls = 0.f, bp = -1.f; int ba_ = 0;
    #pragma unroll
    for (int k = 0; k < 20; ++k) {
        float pc = expf(v[k] - gm);
        ls += pc;
        if (pc > bp) { bp = pc; ba_ = 4 * k + q; }
    }
    float gs = ls;
    gs += __shfl_xor(gs, 1);
    gs += __shfl_xor(gs, 2);
    {
        float bp2 = __shfl_xor(bp, 1); int ba2 = __shfl_xor(ba_, 1);
        if (bp2 > bp || (bp2 == bp && ba2 < ba_)) { bp = bp2; ba_ = ba2; }
        bp2 = __shfl_xor(bp, 2); ba2 = __shfl_xor(ba_, 2);
        if (bp2 > bp || (bp2 == bp && ba2 < ba_)) { bp = bp2; ba_ = ba2; }
    }

    if (q != 0) return;                            // leader finishes the anchor

    float obj = cell[a * HW];
    float sig  = 1.f / (1.f + expf(-obj));
    float conf = sig * (bp / gs);

    // bucket valid boxes per class (key: conf desc, then idx asc via ~idx)
    if (conf >= 0.001f) {                          // == (conf_f32 >= 0.001 as f64)
        int pos = atomicAdd(&cnt[ba_ * CNT_STRIDE], 1);
        if (pos < CAP)
            bucket[ba_ * CAP + pos] = ((u64)__float_as_uint(conf) << 32) | (u64)(~(u32)n);
    }

    const float* regp = cell + (243 + a * 4) * HW;
    float tx = regp[0];
    float ty = regp[HW];
    float tw = regp[2 * HW];
    float th = regp[3 * HW];
    float sx = 1.f / (1.f + expf(-tx));
    float sy = 1.f / (1.f + expf(-ty));
    float cx = (sx + (float)gx) * (float)strd;
    float cy = (sy + (float)gy) * (float)strd;
    int ai = lvl * 3 + a;
    float w  = expf(tw) * c_AW[ai];
    float h  = expf(th) * c_AH[ai];
    float hx = w * 0.5f, hy = h * 0.5f;
    float x1 = (cx - hx) / 640.0f;
    float y1 = (cy - hy) / 640.0f;
    float x2 = (cx + hx) / 640.0f;
    float y2 = (cy + hy) / 640.0f;
    x1 = fminf(fmaxf(x1, 0.f), 1.f);
    y1 = fminf(fmaxf(y1, 0.f), 1.f);
    x2 = fminf(fmaxf(x2, 0.f), 1.f);
    y2 = fminf(fmaxf(y2, 0.f), 1.f);

    out[n * 4 + 0] = x1;
    out[n * 4 + 1] = y1;
    out[n * 4 + 2] = x2;
    out[n * 4 + 3] = y2;
    out[100800 + n] = conf;
    out[126000 + n] = (float)ba_;
    out[151200 + n] = 0.0f;                        // keep default
}

// ---------------- per-class NMS: sort + ballot-tiled mask + register scan ----------------
__global__ __launch_bounds__(512)
void nms_kernel(const int* __restrict__ cnt,
                const u64* __restrict__ bucket,
                const float* __restrict__ bboxes,   // = d_out (clipped boxes)
                float* __restrict__ out_keep)
{
    const int c = blockIdx.x;
    const int tid = threadIdx.x;
    const int wave = tid >> 6, lane = tid & 63;

    __shared__ u64  skey[CAP];                       // 4 KB
    __shared__ float sx1[CAP], sy1[CAP], sx2[CAP], sy2[CAP], sar[CAP];  // 10 KB
    __shared__ int  sgi[CAP];                        // 2 KB
    __shared__ u64  maskT[CAP * NW];                 // 32 KB; maskT[j*8+w]: bits i (word w) with i<j & IoU>=thr

    const int M = min(cnt[c * CNT_STRIDE], CAP);

    // zero maskT (stride-512 u64 -> 2-way bank alias, free)
    #pragma unroll
    for (int z = 0; z < 8; ++z) maskT[tid + (z << 9)] = 0ull;

    u64 ke = 0;
    if (tid < M) { ke = bucket[c * CAP + tid]; skey[tid] = ke; }
    __syncthreads();

    // rank sort via broadcast LDS reads, unrolled x4 to batch loads
    if (tid < M) {
        int rank = 0;
        int j = 0;
        for (; j + 4 <= M; j += 4) {
            u64 a0 = skey[j], a1 = skey[j+1], a2 = skey[j+2], a3 = skey[j+3];
            rank += (int)(a0 > ke) + (int)(a1 > ke) + (int)(a2 > ke) + (int)(a3 > ke);
        }
        for (; j < M; ++j) rank += (int)(skey[j] > ke);

        u32 gi = ~(u32)ke;                           // original anchor index
        const float4 b = *(const float4*)(bboxes + gi * 4);
        float off = 4.0f * (float)c;                 // class-offset: ref computes IoU on offset boxes
        float x1 = b.x + off, y1 = b.y + off, x2 = b.z + off, y2 = b.w + off;
        sx1[rank] = x1; sy1[rank] = y1; sx2[rank] = x2; sy2[rank] = y2;
        sar[rank] = (x2 - x1) * (y2 - y1);
        sgi[rank] = (int)gi;
    }
    __syncthreads();

    // mask build: upper-tri 64x64 tiles; lane = row (box in regs), cols broadcast; ballot -> word
    const int MW = (M + 63) >> 6;
    const int ntiles = (MW * (MW + 1)) >> 1;
    for (int t = wave; t < ntiles; t += 8) {
        int rw = 0, acc = 0;
        while (t >= acc + (MW - rw)) { acc += MW - rw; ++rw; }
        const int cw = rw + (t - acc);
        const int i  = (rw << 6) + lane;
        const bool iv = (i < M);
        const float bx1 = sx1[i], by1 = sy1[i], bx2 = sx2[i], by2 = sy2[i], ba = sar[i];
        const int c0 = cw << 6;
        const int c1 = min(c0 + 64, M);
        for (int j = c0; j < c1; ++j) {
            float jx1 = sx1[j], jy1 = sy1[j], jx2 = sx2[j], jy2 = sy2[j], ja = sar[j];
            float xx1 = fmaxf(bx1, jx1);
            float yy1 = fmaxf(by1, jy1);
            float xx2 = fminf(bx2, jx2);
            float yy2 = fminf(by2, jy2);
            float ww = fmaxf(1e-28f, xx2 - xx1);
            float hh = fmaxf(1e-28f, yy2 - yy1);
            float inter = ww * hh;
            float ovr = inter / (ba + ja - inter + 1e-14f);   // same op order as ref (IoU bit-symmetric)
            u64 bal = __ballot(iv && (i < j) && (ovr >= 0.6f));
            if (lane == 0) maskT[j * NW + rw] = bal;
        }
    }
    __syncthreads();

    // scan: all lanes redundantly track kept words in NAMED registers (static indexing)
    u64 kk0 = 0, kk1 = 0, kk2 = 0, kk3 = 0, kk4 = 0, kk5 = 0, kk6 = 0, kk7 = 0;
    if (M > 0) kk0 = 1ull;                           // first box always kept
    // chunk 0
    for (int b = 1; b < 64; ++b) {
        int j = b; if (j >= M) break;
        u64 tst = maskT[j * NW] & kk0;
        if (tst == 0ull) kk0 |= (1ull << b);
    }
    #define SCAN_CHUNK(W, TEST)                                        \
    for (int b = 0; b < 64; ++b) {                                     \
        int j = (W << 6) + b; if (j >= M) break;                       \
        const u64* mr = &maskT[j * NW];                                \
        u64 tst = (TEST);                                              \
        if (tst == 0ull) kk##W |= (1ull << b);                         \
    }
    SCAN_CHUNK(1, (mr[0]&kk0)|(mr[1]&kk1))
    SCAN_CHUNK(2, (mr[0]&kk0)|(mr[1]&kk1)|(mr[2]&kk2))
    SCAN_CHUNK(3, (mr[0]&kk0)|(mr[1]&kk1)|(mr[2]&kk2)|(mr[3]&kk3))
    SCAN_CHUNK(4, (mr[0]&kk0)|(mr[1]&kk1)|(mr[2]&kk2)|(mr[3]&kk3)|(mr[4]&kk4))
    SCAN_CHUNK(5, (mr[0]&kk0)|(mr[1]&kk1)|(mr[2]&kk2)|(mr[3]&kk3)|(mr[4]&kk4)|(mr[5]&kk5))
    SCAN_CHUNK(6, (mr[0]&kk0)|(mr[1]&kk1)|(mr[2]&kk2)|(mr[3]&kk3)|(mr[4]&kk4)|(mr[5]&kk5)|(mr[6]&kk6))
    SCAN_CHUNK(7, (mr[0]&kk0)|(mr[1]&kk1)|(mr[2]&kk2)|(mr[3]&kk3)|(mr[4]&kk4)|(mr[5]&kk5)|(mr[6]&kk6)|(mr[7]&kk7))
    #undef SCAN_CHUNK

    // keep-write: wave w owns word w
    u64 kw = (wave == 0) ? kk0 : (wave == 1) ? kk1 : (wave == 2) ? kk2 : (wave == 3) ? kk3 :
             (wave == 4) ? kk4 : (wave == 5) ? kk5 : (wave == 6) ? kk6 : kk7;
    int i = (wave << 6) + lane;
    if (i < M && ((kw >> lane) & 1ull)) out_keep[sgi[i]] = 1.0f;
}

extern "C" void kernel_launch(void* const* d_in, const int* in_sizes, int n_in,
                              void* d_out, int out_size, void* d_ws, size_t ws_size,
                              hipStream_t stream) {
    const float* p0 = (const float*)d_in[0];
    const float* p1 = (const float*)d_in[1];
    const float* p2 = (const float*)d_in[2];
    float* out = (float*)d_out;

    char* ws = (char*)d_ws;
    int* cnt    = (int*)ws;                      // 80*16 ints = 5120 B (zeroed each launch)
    u64* bucket = (u64*)(ws + 5120);             // 80*512*8 = 327680 B  (total 332800 B)

    hipMemsetAsync(cnt, 0, NCLS * CNT_STRIDE * sizeof(int), stream);
    decode_kernel<<<(N_TOT * 4 + 255) / 256, 256, 0, stream>>>(p0, p1, p2, cnt, bucket, out);
    nms_kernel<<<NCLS, 512, 0, stream>>>(cnt, bucket, out, out + 151200);
}